// Round 20
// baseline (1167.812 us; speedup 1.0000x reference)
//
#include <hip/hip_runtime.h>

// RecurrentSNN: B=256, T=1024, F=64, H=512, O=64
// out = concat(mem_rec [B,T,O], spk_rec [B,T,O]) f32.
//
// Round-20: chunk-pipelined co-scheduling. A (layer-1 GEMV) and C
// (layer-2 GEMV) are both latency-bound (~70% idle issue slots) and
// independent across chunks: A(c+1) needs only x; C(c) needs only B(c).
// Merge them into one launch, role by blockIdx PARITY (per-CU mix), with
// ping-pong cur1[2]/cout[2] buffers. Role bodies are round-19 verbatim
// (bit-exact). Sequence:
//   AC(A:0) ; B(0) ; { AC(A:c+1 || C:c) ; D(c) ; B(c+1) } for c=0..nch-1.
// If co-residency fills stalls: ~max(A,C) per AC launch (-~300us total).
// If the scalar/K-cache pipe is a shared per-CU throughput wall: neutral.
// Fallback: round-19 serial 4-kernel path if ws can't hold double buffers.
// absmax must stay exactly 0.04394531.

namespace {
constexpr int kB = 256;
constexpr int kT = 1024;
constexpr int kF = 64;
constexpr int kH = 512;
constexpr int kO = 64;
constexpr float kBeta = 0.9f;
constexpr float kThresh = 1.0f;
}  // namespace

typedef __attribute__((ext_vector_type(16))) float f32x16;

#define PIN8(p)                                                            \
  asm volatile("" : "+v"((p)[0]), "+v"((p)[1]), "+v"((p)[2]),              \
                    "+v"((p)[3]), "+v"((p)[4]), "+v"((p)[5]),              \
                    "+v"((p)[6]), "+v"((p)[7]))

#define BARRIER() asm volatile("s_waitcnt lgkmcnt(0)\n\ts_barrier" ::: "memory")

// ======================= role bodies (r19 verbatim) =======================
#define SX(i) ((i) < 16 ? sx0[(i)] : (i) < 32 ? sx1[(i)-16]                \
             : (i) < 48 ? sx2[(i)-32] : sx3[(i)-48])
#define AQ(q)                                                              \
  c0 = fmaf(SX(4*(q)+0), w[4*(q)+0], c0);                                  \
  c1 = fmaf(SX(4*(q)+1), w[4*(q)+1], c1);                                  \
  c2 = fmaf(SX(4*(q)+2), w[4*(q)+2], c2);                                  \
  c3 = fmaf(SX(4*(q)+3), w[4*(q)+3], c3);

__device__ __forceinline__ void roleA(const float* __restrict__ x,
                                      const float* __restrict__ W_in,
                                      const float* __restrict__ b_in,
                                      float* __restrict__ cur1,
                                      int t0, int ntc, int l2ntc, int abid) {
  const int l = threadIdx.x & 63;
  const int s = threadIdx.x >> 6;
  const int h = s * 64 + l;

  float w[64];
  {
    const float4* wiv = reinterpret_cast<const float4*>(W_in) + h * 16;
#pragma unroll
    for (int q = 0; q < 16; ++q) {
      const float4 v = wiv[q];
      w[4*q+0] = v.x; w[4*q+1] = v.y; w[4*q+2] = v.z; w[4*q+3] = v.w;
    }
  }
  float binh = b_in[h];
  PIN8(w + 0);  PIN8(w + 8);  PIN8(w + 16); PIN8(w + 24);
  PIN8(w + 32); PIN8(w + 40); PIN8(w + 48); PIN8(w + 56);
  asm volatile("" : "+v"(binh));

  const int row0 = abid * 64;
#pragma unroll 1
  for (int r = 0; r < 64; ++r) {
    const int row = row0 + r;
    const int b = row >> l2ntc;
    const int tc = row & (ntc - 1);
    const float* xp = x + ((size_t)b * kT + (size_t)(t0 + tc)) * kF;
    f32x16 sx0, sx1, sx2, sx3;
    asm volatile("s_load_dwordx16 %0, %4, 0x0\n\t"
                 "s_load_dwordx16 %1, %4, 0x40\n\t"
                 "s_load_dwordx16 %2, %4, 0x80\n\t"
                 "s_load_dwordx16 %3, %4, 0xc0"
                 : "=&s"(sx0), "=&s"(sx1), "=&s"(sx2), "=&s"(sx3)
                 : "s"(xp));
    asm volatile("s_waitcnt lgkmcnt(0)"
                 : "+s"(sx0), "+s"(sx1), "+s"(sx2), "+s"(sx3) :: "memory");
    float c0 = binh, c1 = 0.0f, c2 = 0.0f, c3 = 0.0f;
    AQ(0) AQ(1) AQ(2) AQ(3) AQ(4) AQ(5) AQ(6) AQ(7)
    AQ(8) AQ(9) AQ(10) AQ(11) AQ(12) AQ(13) AQ(14) AQ(15)
    cur1[(size_t)row * kH + h] = (c0 + c1) + (c2 + c3);
  }
}

#define SC(i) ((i) < 16 ? m0[(i)] : (i) < 32 ? m1[(i)-16]                  \
             : (i) < 48 ? m2[(i)-32] : m3[(i)-48])

#define CROW(rr)                                                           \
  do {                                                                     \
    const float* sp = spkrow + (size_t)(rr) * kH;                          \
    f32x16 m0, m1, m2, m3;                                                 \
    asm volatile("s_load_dwordx16 %0, %4, 0x0\n\t"                         \
                 "s_load_dwordx16 %1, %4, 0x40\n\t"                        \
                 "s_load_dwordx16 %2, %4, 0x80\n\t"                        \
                 "s_load_dwordx16 %3, %4, 0xc0"                            \
                 : "=&s"(m0), "=&s"(m1), "=&s"(m2), "=&s"(m3)              \
                 : "s"(sp));                                               \
    asm volatile("s_waitcnt lgkmcnt(0)"                                    \
                 : "+s"(m0), "+s"(m1), "+s"(m2), "+s"(m3) :: "memory");    \
    float a0 = 0.0f, a1 = 0.0f, a2 = 0.0f, a3 = 0.0f;                      \
    _Pragma("unroll") for (int q = 0; q < 16; ++q) {                       \
      a0 = fmaf(SC(4 * q + 0), wout[4 * q + 0], a0);                       \
      a1 = fmaf(SC(4 * q + 1), wout[4 * q + 1], a1);                       \
      a2 = fmaf(SC(4 * q + 2), wout[4 * q + 2], a2);                       \
      a3 = fmaf(SC(4 * q + 3), wout[4 * q + 3], a3);                       \
    }                                                                      \
    red[buf][rr][s][o] = (a0 + a1) + (a2 + a3);                            \
  } while (0)

__device__ __forceinline__ void roleC(const float* __restrict__ spk,
                                      const float* __restrict__ W_out,
                                      const float* __restrict__ b_out,
                                      float* __restrict__ cout, int cbid,
                                      float (*red)[8][8][64]) {
  const int j = threadIdx.x;
  const int o = j & 63;
  const int s = j >> 6;
  const int s_u = __builtin_amdgcn_readfirstlane(s);
  const size_t row0 = (size_t)cbid * 64;

  float wout[64];
  {
    const float4* wov =
        reinterpret_cast<const float4*>(W_out) + o * (kH / 4) + s * 16;
#pragma unroll
    for (int q = 0; q < 16; ++q) {
      const float4 v = wov[q];
      wout[4*q+0] = v.x; wout[4*q+1] = v.y;
      wout[4*q+2] = v.z; wout[4*q+3] = v.w;
    }
  }
  float bout = b_out[o];
  PIN8(wout + 0);  PIN8(wout + 8);  PIN8(wout + 16); PIN8(wout + 24);
  PIN8(wout + 32); PIN8(wout + 40); PIN8(wout + 48); PIN8(wout + 56);
  asm volatile("" : "+v"(bout));

#pragma unroll 1
  for (int rb = 0; rb < 64; rb += 8) {
    const int buf = (rb >> 3) & 1;
    const float* spkrow = spk + (row0 + (size_t)rb) * kH + s_u * 64;

    CROW(0); CROW(1); CROW(2); CROW(3);
    CROW(4); CROW(5); CROW(6); CROW(7);

    BARRIER();

    float co = bout;
    co += red[buf][s][0][o]; co += red[buf][s][1][o];
    co += red[buf][s][2][o]; co += red[buf][s][3][o];
    co += red[buf][s][4][o]; co += red[buf][s][5][o];
    co += red[buf][s][6][o]; co += red[buf][s][7][o];
    cout[(row0 + (size_t)(rb + s)) * kO + o] = co;
  }
}

// ======================= AC: A(c+1) || C(c), role by parity ===============
__global__ __launch_bounds__(512)
void snn_AC(const float* __restrict__ x, const float* __restrict__ W_in,
            const float* __restrict__ b_in, float* __restrict__ cur1A,
            const float* __restrict__ spkC, const float* __restrict__ W_out,
            const float* __restrict__ b_out, float* __restrict__ coutC,
            int tA0, int ntc, int l2ntc, int doA, int doC) {
  __shared__ float red[2][8][8][64];  // used by C role only (16 KB)
  const int bid = blockIdx.x >> 1;
  if (blockIdx.x & 1) {
    if (doC) roleC(spkC, W_out, b_out, coutC, bid, red);
  } else {
    if (doA) roleA(x, W_in, b_in, cur1A, tA0, ntc, l2ntc, bid);
  }
}

// ======================= serial A / C (fallback path) =====================
__global__ __launch_bounds__(512)
void snn_curA(const float* __restrict__ x, const float* __restrict__ W_in,
              const float* __restrict__ b_in, float* __restrict__ cur1,
              int t0, int ntc, int l2ntc) {
  roleA(x, W_in, b_in, cur1, t0, ntc, l2ntc, blockIdx.x);
}

__global__ __launch_bounds__(512)
void snn_coutC(const float* __restrict__ spk, const float* __restrict__ W_out,
               const float* __restrict__ b_out, float* __restrict__ cout,
               int ntc) {
  __shared__ float red[2][8][8][64];
  roleC(spk, W_out, b_out, cout, blockIdx.x, red);
}

// ======================= B: layer-1 scan (per b,h) ========================
#define BSTEP(fk, tt)                                                      \
  do {                                                                     \
    mem1 = kBeta * mem1 + (fk) - rst1;                                     \
    const bool pr = mem1 > kThresh;                                        \
    rst1 = pr ? 1.0f : 0.0f;                                               \
    cp[(size_t)(tt) * kH] = rst1;  /* spike overwrites cur1 slot */        \
    const int tn_ = ((tt) + 8 < ntc) ? (tt) + 8 : ntc - 1;                 \
    fk = cp[(size_t)tn_ * kH];                                             \
  } while (0)

__global__ __launch_bounds__(512)
void snn_scanB(float* __restrict__ cs, float* __restrict__ state,
               int t0, int ntc) {
  const int b = blockIdx.x;
  const int h = threadIdx.x;
  float* m1s = state;
  float* r1s = state + kB * kH;
  const int idx = b * kH + h;
  float mem1 = 0.0f, rst1 = 0.0f;
  if (t0 != 0) { mem1 = m1s[idx]; rst1 = r1s[idx]; }

  float* cp = cs + (size_t)b * ntc * kH + h;
  float f0 = cp[0 * (size_t)kH], f1 = cp[1 * (size_t)kH];
  float f2 = cp[2 * (size_t)kH], f3 = cp[3 * (size_t)kH];
  float f4 = cp[4 * (size_t)kH], f5 = cp[5 * (size_t)kH];
  float f6 = cp[6 * (size_t)kH], f7 = cp[7 * (size_t)kH];

#pragma unroll 1
  for (int t = 0; t < ntc; t += 8) {
    BSTEP(f0, t + 0); BSTEP(f1, t + 1); BSTEP(f2, t + 2); BSTEP(f3, t + 3);
    BSTEP(f4, t + 4); BSTEP(f5, t + 5); BSTEP(f6, t + 6); BSTEP(f7, t + 7);
  }
  m1s[idx] = mem1;
  r1s[idx] = rst1;
}

// ======================= D: layer-2 scan (per b,o) ========================
#define DSTEP(gk, tt)                                                      \
  do {                                                                     \
    memo = kBeta * memo + (gk) - rsto;                                     \
    const float so = (memo > kThresh) ? 1.0f : 0.0f;                       \
    rsto = so;                                                             \
    om[(size_t)(tt) * kO] = memo;                                          \
    os[(size_t)(tt) * kO] = so;                                            \
    const int tn_ = ((tt) + 8 < ntc) ? (tt) + 8 : ntc - 1;                 \
    gk = dp[(size_t)tn_ * kO];                                             \
  } while (0)

__global__ __launch_bounds__(64)
void snn_memoD(const float* __restrict__ cout, float* __restrict__ out,
               float* __restrict__ state, int t0, int ntc) {
  const int b = blockIdx.x;
  const int o = threadIdx.x;
  float* mos = state + 2 * kB * kH;
  float* ros = mos + kB * kO;
  const int idx = b * kO + o;
  float memo = 0.0f, rsto = 0.0f;
  if (t0 != 0) { memo = mos[idx]; rsto = ros[idx]; }

  const float* dp = cout + (size_t)b * ntc * kO + o;
  float* om = out + ((size_t)b * kT + t0) * kO + o;
  float* os = om + (size_t)kB * kT * kO;

  float g0 = dp[0 * (size_t)kO], g1 = dp[1 * (size_t)kO];
  float g2 = dp[2 * (size_t)kO], g3 = dp[3 * (size_t)kO];
  float g4 = dp[4 * (size_t)kO], g5 = dp[5 * (size_t)kO];
  float g6 = dp[6 * (size_t)kO], g7 = dp[7 * (size_t)kO];

#pragma unroll 1
  for (int t = 0; t < ntc; t += 8) {
    DSTEP(g0, t + 0); DSTEP(g1, t + 1); DSTEP(g2, t + 2); DSTEP(g3, t + 3);
    DSTEP(g4, t + 4); DSTEP(g5, t + 5); DSTEP(g6, t + 6); DSTEP(g7, t + 7);
  }
  mos[idx] = memo;
  ros[idx] = rsto;
}

// ======================= host ==============================================
extern "C" void kernel_launch(void* const* d_in, const int* in_sizes, int n_in,
                              void* d_out, int out_size, void* d_ws,
                              size_t ws_size, hipStream_t stream) {
  const float* x = (const float*)d_in[0];
  const float* W_in = (const float*)d_in[1];
  const float* b_in = (const float*)d_in[2];
  const float* W_out = (const float*)d_in[3];
  const float* b_out = (const float*)d_in[4];
  float* out = (float*)d_out;

  const size_t state_bytes = ((size_t)2 * kB * kH + 2 * kB * kO) * 4;

  // ---- preferred: pipelined dual-buffer path ----
  int nchp = 0;
  for (int c : {8, 16}) {
    const size_t rows_c = (size_t)kB * (kT / c);
    const size_t need = 2 * rows_c * (kH + kO) * 4 + state_bytes;
    if (need <= ws_size) { nchp = c; break; }
  }

  if (nchp) {
    const int ntc = kT / nchp;
    const int l2ntc = (ntc == 128) ? 7 : 6;
    const size_t rows = (size_t)kB * ntc;
    float* cur1[2];
    float* coutb[2];
    cur1[0] = (float*)d_ws;
    cur1[1] = cur1[0] + rows * kH;
    coutb[0] = cur1[1] + rows * kH;
    coutb[1] = coutb[0] + rows * kO;
    float* state = coutb[1] + rows * kO;

    const int gA = (int)(rows / 64);  // == gC
    const dim3 gAC(2 * gA);

    // prologue: A(0), B(0)
    hipLaunchKernelGGL(snn_AC, gAC, dim3(512), 0, stream,
                       x, W_in, b_in, cur1[0], cur1[0], W_out, b_out,
                       coutb[0], 0, ntc, l2ntc, 1, 0);
    hipLaunchKernelGGL(snn_scanB, dim3(kB), dim3(512), 0, stream,
                       cur1[0], state, 0, ntc);

    for (int c = 0; c < nchp; ++c) {
      const int na = c + 1;
      hipLaunchKernelGGL(snn_AC, gAC, dim3(512), 0, stream,
                         x, W_in, b_in, cur1[na & 1], cur1[c & 1],
                         W_out, b_out, coutb[c & 1],
                         na * ntc, ntc, l2ntc, (na < nchp) ? 1 : 0, 1);
      hipLaunchKernelGGL(snn_memoD, dim3(kB), dim3(64), 0, stream,
                         coutb[c & 1], out, state, c * ntc, ntc);
      if (na < nchp) {
        hipLaunchKernelGGL(snn_scanB, dim3(kB), dim3(512), 0, stream,
                           cur1[na & 1], state, na * ntc, ntc);
      }
    }
    return;
  }

  // ---- fallback: round-19 serial path ----
  int nch = 0;
  for (int c : {4, 8, 16}) {
    const int ntc_c = kT / c;
    const size_t need = (size_t)kB * ntc_c * (kH + kO) * 4 + state_bytes;
    if (need <= ws_size) { nch = c; break; }
  }
  if (!nch) return;  // ws too small for any path (not expected)

  const int ntc = kT / nch;
  const int l2ntc = (ntc == 256) ? 8 : (ntc == 128) ? 7 : 6;
  float* cur1 = (float*)d_ws;
  float* coutb = cur1 + (size_t)kB * ntc * kH;
  float* state = coutb + (size_t)kB * ntc * kO;

  const int rows = kB * ntc;
  const int gA = rows / 64;
  const int gC = rows / 64;

  for (int c = 0; c < nch; ++c) {
    const int t0 = c * ntc;
    hipLaunchKernelGGL(snn_curA, dim3(gA), dim3(512), 0, stream,
                       x, W_in, b_in, cur1, t0, ntc, l2ntc);
    hipLaunchKernelGGL(snn_scanB, dim3(kB), dim3(512), 0, stream,
                       cur1, state, t0, ntc);
    hipLaunchKernelGGL(snn_coutC, dim3(gC), dim3(512), 0, stream,
                       cur1, W_out, b_out, coutb, ntc);
    hipLaunchKernelGGL(snn_memoD, dim3(kB), dim3(64), 0, stream,
                       coutb, out, state, t0, ntc);
  }
}

// Round 21
// 1027.512 us; speedup vs baseline: 1.1365x; 1.1365x over previous
//
#include <hip/hip_runtime.h>

// RecurrentSNN: B=256, T=1024, F=64, H=512, O=64
// out = concat(mem_rec [B,T,O], spk_rec [B,T,O]) f32.
//
// Round-21: restore round-19 (best measured, 1023us; reproduced twice).
// Session ledger: every broadcast mechanism and scheduling lever measured;
// scalar-pipe GEMV operand broadcast (~33cy/s_load service, shared per-CU
// wall confirmed by r20's neutral co-scheduling test) + bit-exact-chain
// constraint (absmax margin 0.044/0.055 forbids MFMA/reassociation) set
// the practical floor at ~1.02ms for this op shape.
// Structure: A thread=h scalar-x GEMV | B in-place scan | C scalar-spike
// GEMV | D scan; nch=4 chunks, all intermediates L3-resident.

namespace {
constexpr int kB = 256;
constexpr int kT = 1024;
constexpr int kF = 64;
constexpr int kH = 512;
constexpr int kO = 64;
constexpr float kBeta = 0.9f;
constexpr float kThresh = 1.0f;
}  // namespace

typedef __attribute__((ext_vector_type(16))) float f32x16;

#define PIN8(p)                                                            \
  asm volatile("" : "+v"((p)[0]), "+v"((p)[1]), "+v"((p)[2]),              \
                    "+v"((p)[3]), "+v"((p)[4]), "+v"((p)[5]),              \
                    "+v"((p)[6]), "+v"((p)[7]))

#define BARRIER() asm volatile("s_waitcnt lgkmcnt(0)\n\ts_barrier" ::: "memory")

// ======================= A: cur1 = x @ W_in^T + b_in ======================
#define SX(i) ((i) < 16 ? sx0[(i)] : (i) < 32 ? sx1[(i)-16]                \
             : (i) < 48 ? sx2[(i)-32] : sx3[(i)-48])
#define AQ(q)                                                              \
  c0 = fmaf(SX(4*(q)+0), w[4*(q)+0], c0);                                  \
  c1 = fmaf(SX(4*(q)+1), w[4*(q)+1], c1);                                  \
  c2 = fmaf(SX(4*(q)+2), w[4*(q)+2], c2);                                  \
  c3 = fmaf(SX(4*(q)+3), w[4*(q)+3], c3);

__global__ __launch_bounds__(512)
void snn_curA(const float* __restrict__ x, const float* __restrict__ W_in,
              const float* __restrict__ b_in, float* __restrict__ cur1,
              int t0, int ntc, int l2ntc, int rpb) {
  const int l = threadIdx.x & 63;
  const int s = threadIdx.x >> 6;
  const int h = s * 64 + l;

  // W_in row h resident (per-lane gather, ONCE per kernel)
  float w[64];
  {
    const float4* wiv = reinterpret_cast<const float4*>(W_in) + h * 16;
#pragma unroll
    for (int q = 0; q < 16; ++q) {
      const float4 v = wiv[q];
      w[4*q+0] = v.x; w[4*q+1] = v.y; w[4*q+2] = v.z; w[4*q+3] = v.w;
    }
  }
  float binh = b_in[h];
  PIN8(w + 0);  PIN8(w + 8);  PIN8(w + 16); PIN8(w + 24);
  PIN8(w + 32); PIN8(w + 40); PIN8(w + 48); PIN8(w + 56);
  asm volatile("" : "+v"(binh));

  const int row0 = blockIdx.x * rpb;
#pragma unroll 1
  for (int r = 0; r < rpb; ++r) {
    const int row = row0 + r;
    const int b = row >> l2ntc;
    const int tc = row & (ntc - 1);
    const float* xp = x + ((size_t)b * kT + (size_t)(t0 + tc)) * kF;
    f32x16 sx0, sx1, sx2, sx3;
    asm volatile("s_load_dwordx16 %0, %4, 0x0\n\t"
                 "s_load_dwordx16 %1, %4, 0x40\n\t"
                 "s_load_dwordx16 %2, %4, 0x80\n\t"
                 "s_load_dwordx16 %3, %4, 0xc0"
                 : "=&s"(sx0), "=&s"(sx1), "=&s"(sx2), "=&s"(sx3)
                 : "s"(xp));
    asm volatile("s_waitcnt lgkmcnt(0)"
                 : "+s"(sx0), "+s"(sx1), "+s"(sx2), "+s"(sx3) :: "memory");
    float c0 = binh, c1 = 0.0f, c2 = 0.0f, c3 = 0.0f;
    AQ(0) AQ(1) AQ(2) AQ(3) AQ(4) AQ(5) AQ(6) AQ(7)
    AQ(8) AQ(9) AQ(10) AQ(11) AQ(12) AQ(13) AQ(14) AQ(15)
    cur1[(size_t)row * kH + h] = (c0 + c1) + (c2 + c3);
  }
}

// ======================= B: layer-1 scan (per b,h) ========================
#define BSTEP(fk, tt)                                                      \
  do {                                                                     \
    mem1 = kBeta * mem1 + (fk) - rst1;                                     \
    const bool pr = mem1 > kThresh;                                        \
    rst1 = pr ? 1.0f : 0.0f;                                               \
    cp[(size_t)(tt) * kH] = rst1;  /* spike overwrites cur1 slot */        \
    const int tn_ = ((tt) + 8 < ntc) ? (tt) + 8 : ntc - 1;                 \
    fk = cp[(size_t)tn_ * kH];     /* prefetch (clamped ones unused) */    \
  } while (0)

__global__ __launch_bounds__(512)
void snn_scanB(float* __restrict__ cs, float* __restrict__ state,
               int t0, int ntc) {
  const int b = blockIdx.x;
  const int h = threadIdx.x;
  float* m1s = state;
  float* r1s = state + kB * kH;
  const int idx = b * kH + h;
  float mem1 = 0.0f, rst1 = 0.0f;
  if (t0 != 0) { mem1 = m1s[idx]; rst1 = r1s[idx]; }

  float* cp = cs + (size_t)b * ntc * kH + h;
  float f0 = cp[0 * (size_t)kH], f1 = cp[1 * (size_t)kH];
  float f2 = cp[2 * (size_t)kH], f3 = cp[3 * (size_t)kH];
  float f4 = cp[4 * (size_t)kH], f5 = cp[5 * (size_t)kH];
  float f6 = cp[6 * (size_t)kH], f7 = cp[7 * (size_t)kH];

#pragma unroll 1
  for (int t = 0; t < ntc; t += 8) {
    BSTEP(f0, t + 0); BSTEP(f1, t + 1); BSTEP(f2, t + 2); BSTEP(f3, t + 3);
    BSTEP(f4, t + 4); BSTEP(f5, t + 5); BSTEP(f6, t + 6); BSTEP(f7, t + 7);
  }
  m1s[idx] = mem1;
  r1s[idx] = rst1;
}

// ======================= C: cur_out = spikes @ W_out^T + b_out ============
#define SC(i) ((i) < 16 ? m0[(i)] : (i) < 32 ? m1[(i)-16]                  \
             : (i) < 48 ? m2[(i)-32] : m3[(i)-48])

#define CROW(rr)                                                           \
  do {                                                                     \
    const float* sp = spkrow + (size_t)(rr) * kH;                          \
    f32x16 m0, m1, m2, m3;                                                 \
    asm volatile("s_load_dwordx16 %0, %4, 0x0\n\t"                         \
                 "s_load_dwordx16 %1, %4, 0x40\n\t"                        \
                 "s_load_dwordx16 %2, %4, 0x80\n\t"                        \
                 "s_load_dwordx16 %3, %4, 0xc0"                            \
                 : "=&s"(m0), "=&s"(m1), "=&s"(m2), "=&s"(m3)              \
                 : "s"(sp));                                               \
    asm volatile("s_waitcnt lgkmcnt(0)"                                    \
                 : "+s"(m0), "+s"(m1), "+s"(m2), "+s"(m3) :: "memory");    \
    float a0 = 0.0f, a1 = 0.0f, a2 = 0.0f, a3 = 0.0f;                      \
    _Pragma("unroll") for (int q = 0; q < 16; ++q) {                       \
      a0 = fmaf(SC(4 * q + 0), wout[4 * q + 0], a0);                       \
      a1 = fmaf(SC(4 * q + 1), wout[4 * q + 1], a1);                       \
      a2 = fmaf(SC(4 * q + 2), wout[4 * q + 2], a2);                       \
      a3 = fmaf(SC(4 * q + 3), wout[4 * q + 3], a3);                       \
    }                                                                      \
    red[buf][rr][s][o] = (a0 + a1) + (a2 + a3);                            \
  } while (0)

__global__ __launch_bounds__(512)
void snn_coutC(const float* __restrict__ spk, const float* __restrict__ W_out,
               const float* __restrict__ b_out, float* __restrict__ cout,
               int ntc) {
  const int j = threadIdx.x;
  const int o = j & 63;
  const int s = j >> 6;
  const int s_u = __builtin_amdgcn_readfirstlane(s);  // SGPR-addressable
  const size_t row0 = (size_t)blockIdx.x * 64;

  __shared__ float red[2][8][8][64];  // [buf][rowInBatch][slice][o]

  float wout[64];
  {
    const float4* wov =
        reinterpret_cast<const float4*>(W_out) + o * (kH / 4) + s * 16;
#pragma unroll
    for (int q = 0; q < 16; ++q) {
      const float4 v = wov[q];
      wout[4*q+0] = v.x; wout[4*q+1] = v.y;
      wout[4*q+2] = v.z; wout[4*q+3] = v.w;
    }
  }
  float bout = b_out[o];
  PIN8(wout + 0);  PIN8(wout + 8);  PIN8(wout + 16); PIN8(wout + 24);
  PIN8(wout + 32); PIN8(wout + 40); PIN8(wout + 48); PIN8(wout + 56);
  asm volatile("" : "+v"(bout));

#pragma unroll 1
  for (int rb = 0; rb < 64; rb += 8) {
    const int buf = (rb >> 3) & 1;
    const float* spkrow = spk + (row0 + (size_t)rb) * kH + s_u * 64;

    CROW(0); CROW(1); CROW(2); CROW(3);
    CROW(4); CROW(5); CROW(6); CROW(7);

    BARRIER();  // red visible; single barrier per batch (dbuf separation)

    // wave s reduces row rb+s and stores (coalesced 256B)
    float co = bout;
    co += red[buf][s][0][o]; co += red[buf][s][1][o];
    co += red[buf][s][2][o]; co += red[buf][s][3][o];
    co += red[buf][s][4][o]; co += red[buf][s][5][o];
    co += red[buf][s][6][o]; co += red[buf][s][7][o];
    cout[(row0 + (size_t)(rb + s)) * kO + o] = co;
  }
}

// ======================= D: layer-2 scan (per b,o) ========================
#define DSTEP(gk, tt)                                                      \
  do {                                                                     \
    memo = kBeta * memo + (gk) - rsto;                                     \
    const float so = (memo > kThresh) ? 1.0f : 0.0f;                       \
    rsto = so;                                                             \
    om[(size_t)(tt) * kO] = memo;                                          \
    os[(size_t)(tt) * kO] = so;                                            \
    const int tn_ = ((tt) + 8 < ntc) ? (tt) + 8 : ntc - 1;                 \
    gk = dp[(size_t)tn_ * kO];                                             \
  } while (0)

__global__ __launch_bounds__(64)
void snn_memoD(const float* __restrict__ cout, float* __restrict__ out,
               float* __restrict__ state, int t0, int ntc) {
  const int b = blockIdx.x;
  const int o = threadIdx.x;
  float* mos = state + 2 * kB * kH;
  float* ros = mos + kB * kO;
  const int idx = b * kO + o;
  float memo = 0.0f, rsto = 0.0f;
  if (t0 != 0) { memo = mos[idx]; rsto = ros[idx]; }

  const float* dp = cout + (size_t)b * ntc * kO + o;
  float* om = out + ((size_t)b * kT + t0) * kO + o;
  float* os = om + (size_t)kB * kT * kO;

  float g0 = dp[0 * (size_t)kO], g1 = dp[1 * (size_t)kO];
  float g2 = dp[2 * (size_t)kO], g3 = dp[3 * (size_t)kO];
  float g4 = dp[4 * (size_t)kO], g5 = dp[5 * (size_t)kO];
  float g6 = dp[6 * (size_t)kO], g7 = dp[7 * (size_t)kO];

#pragma unroll 1
  for (int t = 0; t < ntc; t += 8) {
    DSTEP(g0, t + 0); DSTEP(g1, t + 1); DSTEP(g2, t + 2); DSTEP(g3, t + 3);
    DSTEP(g4, t + 4); DSTEP(g5, t + 5); DSTEP(g6, t + 6); DSTEP(g7, t + 7);
  }
  mos[idx] = memo;
  ros[idx] = rsto;
}

// ======================= fallback (round-5, proven 1101us) ================
__global__ __launch_bounds__(256)
void warm_x_kernel(const float4* __restrict__ p, int n4) {
  float acc = 0.0f;
  for (int i = blockIdx.x * blockDim.x + threadIdx.x; i < n4;
       i += gridDim.x * blockDim.x) {
    const float4 v = p[i];
    acc += v.x + v.y + v.z + v.w;
  }
  asm volatile("" ::"v"(acc));
}

__global__ __launch_bounds__(512)
__attribute__((amdgpu_waves_per_eu(2, 2)))
void snn_fused5(const float* __restrict__ x, const float* __restrict__ W_in,
                const float* __restrict__ b_in,
                const float* __restrict__ W_out,
                const float* __restrict__ b_out, float* __restrict__ out) {
  const int b = blockIdx.x;
  const int j = threadIdx.x;
  const int o = j & 63;
  const int s = j >> 6;
  __shared__ float red[2][8][64];
  float win[kF];
  {
    const float4* wiv = reinterpret_cast<const float4*>(W_in) + j * 16;
#pragma unroll
    for (int q = 0; q < 16; ++q) {
      const float4 v = wiv[q];
      win[4 * q] = v.x; win[4 * q + 1] = v.y;
      win[4 * q + 2] = v.z; win[4 * q + 3] = v.w;
    }
  }
  float wout[64];
  {
    const float4* wov =
        reinterpret_cast<const float4*>(W_out) + o * 128 + s * 16;
#pragma unroll
    for (int q = 0; q < 16; ++q) {
      const float4 v = wov[q];
      wout[4 * q] = v.x; wout[4 * q + 1] = v.y;
      wout[4 * q + 2] = v.z; wout[4 * q + 3] = v.w;
    }
  }
  float bin_j = b_in[j];
  float bout_o = b_out[o];
  PIN8(win + 0);  PIN8(win + 8);  PIN8(win + 16); PIN8(win + 24);
  PIN8(win + 32); PIN8(win + 40); PIN8(win + 48); PIN8(win + 56);
  PIN8(wout + 0);  PIN8(wout + 8);  PIN8(wout + 16); PIN8(wout + 24);
  PIN8(wout + 32); PIN8(wout + 40); PIN8(wout + 48); PIN8(wout + 56);
  asm volatile("" : "+v"(bin_j), "+v"(bout_o));
  float mem1 = 0.0f, rst1 = 0.0f, memo = 0.0f, rsto = 0.0f;
  unsigned long long mask = 0ull;
  const float4* xv = reinterpret_cast<const float4*>(x + (size_t)b * kT * kF);
  float* out_mem = out + (size_t)b * kT * kO + o;
  float* out_spk = out_mem + (size_t)kB * kT * kO;
  float4 x0, x1, x2, x3, x4, x5, x6, x7, x8, x9, x10, x11, x12, x13, x14, x15;
#define LOADX(tt)                                                          \
  do {                                                                     \
    const float4* xp = xv + (size_t)(tt) * 16;                             \
    x0 = xp[0]; x1 = xp[1]; x2 = xp[2]; x3 = xp[3];                        \
    x4 = xp[4]; x5 = xp[5]; x6 = xp[6]; x7 = xp[7];                        \
    x8 = xp[8]; x9 = xp[9]; x10 = xp[10]; x11 = xp[11];                    \
    x12 = xp[12]; x13 = xp[13]; x14 = xp[14]; x15 = xp[15];                \
  } while (0)
#define L1Q(q)                                                             \
  c0 = fmaf(x##q.x, win[4 * q + 0], c0);                                   \
  c1 = fmaf(x##q.y, win[4 * q + 1], c1);                                   \
  c2 = fmaf(x##q.z, win[4 * q + 2], c2);                                   \
  c3 = fmaf(x##q.w, win[4 * q + 3], c3);
#define LAYER1F()                                                          \
  do {                                                                     \
    float c0 = bin_j, c1 = 0.0f, c2 = 0.0f, c3 = 0.0f;                     \
    L1Q(0) L1Q(1) L1Q(2) L1Q(3) L1Q(4) L1Q(5) L1Q(6) L1Q(7)                \
    L1Q(8) L1Q(9) L1Q(10) L1Q(11) L1Q(12) L1Q(13) L1Q(14) L1Q(15)          \
    const float cur1v = (c0 + c1) + (c2 + c3);                             \
    mem1 = kBeta * mem1 + cur1v - rst1;                                    \
    const bool p = mem1 > kThresh;                                         \
    mask = __ballot(p);                                                    \
    rst1 = p ? 1.0f : 0.0f;                                                \
  } while (0)
#define L2QS(q)                                                            \
  {                                                                        \
    const float f0 = ((mlo >> (4 * (q) + 0)) & 1u) ? 1.0f : 0.0f;          \
    const float f1 = ((mlo >> (4 * (q) + 1)) & 1u) ? 1.0f : 0.0f;          \
    const float f2 = ((mlo >> (4 * (q) + 2)) & 1u) ? 1.0f : 0.0f;          \
    const float f3 = ((mlo >> (4 * (q) + 3)) & 1u) ? 1.0f : 0.0f;          \
    a0 = fmaf(f0, wout[4 * (q) + 0], a0);                                  \
    a1 = fmaf(f1, wout[4 * (q) + 1], a1);                                  \
    a2 = fmaf(f2, wout[4 * (q) + 2], a2);                                  \
    a3 = fmaf(f3, wout[4 * (q) + 3], a3);                                  \
  }
#define L2E(acc, q, i)                                                     \
  acc = acc + __uint_as_float(                                             \
      (unsigned)__builtin_amdgcn_sbfe((int)vmhi, 4 * (q) + (i)-32, 1) &    \
      __float_as_uint(wout[4 * (q) + (i)]));
#define L2QV(q)                                                            \
  { L2E(a0, q, 0) L2E(a1, q, 1) L2E(a2, q, 2) L2E(a3, q, 3) }
#define LAYER2F(buf)                                                       \
  do {                                                                     \
    const unsigned mlo = (unsigned)mask;                                   \
    unsigned vmhi = (unsigned)(mask >> 32);                                \
    asm volatile("" : "+v"(vmhi));                                         \
    float a0 = 0.0f, a1 = 0.0f, a2 = 0.0f, a3 = 0.0f;                      \
    L2QS(0) L2QS(1) L2QS(2) L2QS(3) L2QS(4) L2QS(5) L2QS(6) L2QS(7)        \
    L2QV(8) L2QV(9) L2QV(10) L2QV(11) L2QV(12) L2QV(13) L2QV(14) L2QV(15)  \
    red[(buf)][s][o] = (a0 + a1) + (a2 + a3);                              \
  } while (0)
  LOADX(0);
  LAYER1F();
  LOADX(1);
  for (int t = 1; t < kT; ++t) {
    LAYER2F((t - 1) & 1);
    BARRIER();
    float r0, r1, r2, r3, r4, r5, r6, r7;
    const int buf = (t - 1) & 1;
    if (s == 0) {
      r0 = red[buf][0][o]; r1 = red[buf][1][o];
      r2 = red[buf][2][o]; r3 = red[buf][3][o];
      r4 = red[buf][4][o]; r5 = red[buf][5][o];
      r6 = red[buf][6][o]; r7 = red[buf][7][o];
    }
    LAYER1F();
    const int tn = (t + 1 < kT) ? (t + 1) : (kT - 1);
    LOADX(tn);
    if (s == 0) {
      float co = bout_o;
      co += r0; co += r1; co += r2; co += r3;
      co += r4; co += r5; co += r6; co += r7;
      memo = kBeta * memo + co - rsto;
      const float so = (memo > kThresh) ? 1.0f : 0.0f;
      rsto = so;
      out_mem[(t - 1) * kO] = memo;
      out_spk[(t - 1) * kO] = so;
    }
  }
  LAYER2F((kT - 1) & 1);
  BARRIER();
  if (s == 0) {
    const int buf = (kT - 1) & 1;
    float co = bout_o;
    co += red[buf][0][o]; co += red[buf][1][o];
    co += red[buf][2][o]; co += red[buf][3][o];
    co += red[buf][4][o]; co += red[buf][5][o];
    co += red[buf][6][o]; co += red[buf][7][o];
    memo = kBeta * memo + co - rsto;
    const float so = (memo > kThresh) ? 1.0f : 0.0f;
    out_mem[(kT - 1) * kO] = memo;
    out_spk[(kT - 1) * kO] = so;
  }
}

// ======================= host ==============================================
extern "C" void kernel_launch(void* const* d_in, const int* in_sizes, int n_in,
                              void* d_out, int out_size, void* d_ws,
                              size_t ws_size, hipStream_t stream) {
  const float* x = (const float*)d_in[0];
  const float* W_in = (const float*)d_in[1];
  const float* b_in = (const float*)d_in[2];
  const float* W_out = (const float*)d_in[3];
  const float* b_out = (const float*)d_in[4];
  float* out = (float*)d_out;

  const size_t state_bytes = ((size_t)2 * kB * kH + 2 * kB * kO) * 4;
  int nch = 0;
  for (int c : {4, 8, 16}) {   // nch=2 would spill cur1 past the 256MB L3
    const int ntc_c = kT / c;
    const size_t need = (size_t)kB * ntc_c * (kH + kO) * 4 + state_bytes;
    if (need <= ws_size) { nch = c; break; }
  }

  if (nch) {
    const int ntc = kT / nch;
    const int l2ntc = (ntc == 256) ? 8 : (ntc == 128) ? 7 : 6;
    float* cur1 = (float*)d_ws;                       // also spike buffer
    float* coutb = cur1 + (size_t)kB * ntc * kH;
    float* state = coutb + (size_t)kB * ntc * kO;

    const int rows = kB * ntc;
    const int rpbA = 64;
    const int gA = rows / rpbA;
    const int gC = rows / 64;

    for (int c = 0; c < nch; ++c) {
      const int t0 = c * ntc;
      hipLaunchKernelGGL(snn_curA, dim3(gA), dim3(512), 0, stream,
                         x, W_in, b_in, cur1, t0, ntc, l2ntc, rpbA);
      hipLaunchKernelGGL(snn_scanB, dim3(kB), dim3(512), 0, stream,
                         cur1, state, t0, ntc);
      hipLaunchKernelGGL(snn_coutC, dim3(gC), dim3(512), 0, stream,
                         cur1, W_out, b_out, coutb, ntc);
      hipLaunchKernelGGL(snn_memoD, dim3(kB), dim3(64), 0, stream,
                         coutb, out, state, t0, ntc);
    }
  } else {
    const int n4 = kB * kT * kF / 4;
    hipLaunchKernelGGL(warm_x_kernel, dim3(1024), dim3(256), 0, stream,
                       (const float4*)x, n4);
    hipLaunchKernelGGL(snn_fused5, dim3(kB), dim3(512), 0, stream,
                       x, W_in, b_in, W_out, b_out, out);
  }
}